// Round 8
// baseline (208.032 us; speedup 1.0000x reference)
//
#include <hip/hip_runtime.h>
#include <hip/hip_bf16.h>

namespace {
constexpr int CB   = 256;   // channels
constexpr int HWp  = 4096;  // 64*64 pixels per plane
constexpr int NB   = 16;    // batch

typedef __bf16    bf16x8 __attribute__((ext_vector_type(8)));
typedef float     f32x4  __attribute__((ext_vector_type(4)));
typedef float     f32x16 __attribute__((ext_vector_type(16)));
typedef _Float16  f16x2  __attribute__((ext_vector_type(2)));
typedef _Float16  f16x8  __attribute__((ext_vector_type(8)));

typedef __attribute__((address_space(1))) void gvoid;  // global
typedef __attribute__((address_space(3))) void svoid;  // LDS

__device__ __forceinline__ unsigned int pack2(float lo, float hi) {
#if __has_builtin(__builtin_amdgcn_cvt_pkrtz)
    return __builtin_bit_cast(unsigned int, __builtin_amdgcn_cvt_pkrtz(lo, hi));
#else
    f16x2 v; v[0] = (_Float16)lo; v[1] = (_Float16)hi;
    return __builtin_bit_cast(unsigned int, v);
#endif
}

// Toeplitz table: entry = one A-fragment lane (8 f16 = 16B).
// index = ((c*31 + r)*4 + kq)*64 + lane
constexpr int TOEP_PER_C = 31 * 4 * 64;
constexpr int HALO_U32   = 94 * 64;      // per-image halo, stride 64 u32, swizzled
// y16 planes are stored with a per-channel pixel ROTATION of c*128 (mod 4096)
// to break the exact-8KB channel stride in gemm's B-gather (HBM channel
// camping).  Rotation is 128-px granular; all access runs are <=32 px within
// 32-aligned chunks, so no run crosses the wrap.
}

// ---------------------------------------------------------------------------
// Kernel 0: prep = BN-accumulator zeroing (bid 0) + pw fp32->bf16 (bid 0..63)
// + Toeplitz A-frag build (bid 64..7999).  A[i,k]=w[r][k-i-1], banded.
// ---------------------------------------------------------------------------
__global__ __launch_bounds__(256) void prep_kernel(
    const float* __restrict__ pw, __hip_bfloat16* __restrict__ pwb,
    const float* __restrict__ dw, uint4* __restrict__ toep,
    float* __restrict__ gsum)
{
    const int bid = blockIdx.x;
    const int tid = threadIdx.x;
    if (bid < 64) {
        if (bid == 0) { gsum[tid] = 0.f; gsum[256 + tid] = 0.f; }
        const int idx = bid * 256 + tid;
        const float4 v = reinterpret_cast<const float4*>(pw)[idx];
        union { __hip_bfloat16 h[4]; uint2 u; } pk;
        pk.h[0] = __float2bfloat16(v.x); pk.h[1] = __float2bfloat16(v.y);
        pk.h[2] = __float2bfloat16(v.z); pk.h[3] = __float2bfloat16(v.w);
        reinterpret_cast<uint2*>(pwb)[idx] = pk.u;
        return;
    }
    const int flat = (bid - 64) * 256 + tid;              // < 256*31*4*64
    const int lane = flat & 63;
    const int kq   = (flat >> 6) & 3;
    const int rc   = flat >> 8;                           // c*31 + r
    const int r    = rc % 31;
    const int c    = rc / 31;
    const int i    = lane & 31;
    const int kbase = kq * 16 + (lane >> 5) * 8;

    const float* __restrict__ wr = dw + (size_t)c * 961 + r * 31;
    union { _Float16 h[8]; uint4 u; } out;
#pragma unroll
    for (int e = 0; e < 8; ++e) {
        const int t = kbase + e - i - 1;
        out.h[e] = (t >= 0 && t <= 30) ? (_Float16)wr[t] : (_Float16)0.f;
    }
    toep[flat] = out.u;
}

// ---------------------------------------------------------------------------
// Kernel 1: depthwise 31x31 conv via MFMA, two images per block (same c).
// Halo per image: 94 x 64 u32 f16-pairs, XOR-swizzled (col ^= (row&7)<<2).
// y written as f16 into workspace, per-channel pixel rotation c*128.
// ---------------------------------------------------------------------------
__global__ __launch_bounds__(256, 3) void dwconv_kernel(
    const float* __restrict__ x, const uint4* __restrict__ toep,
    _Float16* __restrict__ y16, float* __restrict__ gsum, float* __restrict__ gsumsq)
{
    __shared__ unsigned int xs[2 * HALO_U32];   // 48128 B

    const int bid = blockIdx.x;           // bp*256 + c  (c low bits -> XCD = c%8)
    const int c   = bid & 255;
    const int bp  = bid >> 8;
    const int tid = threadIdx.x;

    for (int idx = tid; idx < 2 * HALO_U32 / 4; idx += 256)
        reinterpret_cast<uint4*>(xs)[idx] = uint4{0, 0, 0, 0};
    __syncthreads();

    {
        const int row = tid >> 2;
        const int q   = tid & 3;
        const int hr  = row + 15;
        const int swz = (hr & 7) << 2;
        const int p0  = (8  + q * 8) ^ swz;
        const int p1  = (12 + q * 8) ^ swz;
#pragma unroll
        for (int img = 0; img < 2; ++img) {
            const float4* src = reinterpret_cast<const float4*>(
                x + ((size_t)((bp * 2 + img) * CB + c)) * HWp + row * 64 + q * 16);
            float4 v0 = src[0], v1 = src[1], v2 = src[2], v3 = src[3];
            uint4 a, b;
            a.x = pack2(v0.x, v0.y); a.y = pack2(v0.z, v0.w);
            a.z = pack2(v1.x, v1.y); a.w = pack2(v1.z, v1.w);
            b.x = pack2(v2.x, v2.y); b.y = pack2(v2.z, v2.w);
            b.z = pack2(v3.x, v3.y); b.w = pack2(v3.z, v3.w);
            unsigned int* base = xs + img * HALO_U32 + hr * 64;
            *reinterpret_cast<uint4*>(base + p0) = a;
            *reinterpret_cast<uint4*>(base + p1) = b;
        }
    }
    __syncthreads();

    const int lane = tid & 63;
    const int wid  = tid >> 6;
    const int j    = lane & 31;
    const int half = lane >> 5;
    const int rowb = wid * 16 + (j >> 1);
    const int colb = (j & 1) * 16 + half * 4;
    const uint4* __restrict__ tp = toep + (size_t)c * TOEP_PER_C + lane;

    f32x16 acc0 = {}, acc1 = {};
    uint4 afA[4];
#pragma unroll
    for (int kq = 0; kq < 4; ++kq) afA[kq] = tp[kq * 64];

#pragma unroll 1
    for (int r = 0; r < 31; ++r) {
        uint4 afB[4];
        if (r < 30) {
#pragma unroll
            for (int kq = 0; kq < 4; ++kq) afB[kq] = tp[((r + 1) * 4 + kq) * 64];
        }
        const int row = rowb + r;
        const int swz = (row & 7) << 2;
        const unsigned int* __restrict__ xr = xs + row * 64;
        f16x8 b0[4], b1[4];
#pragma unroll
        for (int kq = 0; kq < 4; ++kq) {
            const int p = (colb + kq * 8) ^ swz;
            b0[kq] = *reinterpret_cast<const f16x8*>(xr + p);
            b1[kq] = *reinterpret_cast<const f16x8*>(xr + HALO_U32 + p);
        }
#pragma unroll
        for (int kq = 0; kq < 4; ++kq)
            acc0 = __builtin_amdgcn_mfma_f32_32x32x16_f16(
                __builtin_bit_cast(f16x8, afA[kq]), b0[kq], acc0, 0, 0, 0);
#pragma unroll
        for (int kq = 0; kq < 4; ++kq)
            acc1 = __builtin_amdgcn_mfma_f32_32x32x16_f16(
                __builtin_bit_cast(f16x8, afA[kq]), b1[kq], acc1, 0, 0, 0);
        if (r < 30) {
#pragma unroll
            for (int kq = 0; kq < 4; ++kq) afA[kq] = afB[kq];
        }
    }

    // Store y as f16, per-channel rotated: pixel' = (pixel + c*128) & 4095.
    // D layout: col j -> (h_sub, w_block); row i = (reg&3)+8*(reg>>2)+4*half.
    const size_t pb0    = ((size_t)(bp * 2 * CB + c)) * HWp;
    const int pixbase   = (rowb * 64 + (j & 1) * 32 + (c << 7)) & 4095;
    const size_t pl0    = pb0 + pixbase + 4 * half;
#pragma unroll
    for (int g = 0; g < 4; ++g) {
        uint2 u0, u1;
        u0.x = pack2(acc0[4 * g + 0], acc0[4 * g + 1]);
        u0.y = pack2(acc0[4 * g + 2], acc0[4 * g + 3]);
        u1.x = pack2(acc1[4 * g + 0], acc1[4 * g + 1]);
        u1.y = pack2(acc1[4 * g + 2], acc1[4 * g + 3]);
        *reinterpret_cast<uint2*>(y16 + pl0 + 8 * g)            = u0;
        *reinterpret_cast<uint2*>(y16 + pl0 + CB * HWp + 8 * g) = u1;
    }

    float s = 0.f, s2 = 0.f;
#pragma unroll
    for (int t = 0; t < 16; ++t) {
        s += acc0[t] + acc1[t];
        s2 = fmaf(acc0[t], acc0[t], s2);
        s2 = fmaf(acc1[t], acc1[t], s2);
    }
#pragma unroll
    for (int off = 32; off > 0; off >>= 1) {
        s  += __shfl_down(s,  off, 64);
        s2 += __shfl_down(s2, off, 64);
    }
    if (lane == 0) {
        atomicAdd(&gsum[c],   s);
        atomicAdd(&gsumsq[c], s2);
    }
}

// ---------------------------------------------------------------------------
// Kernel 2: fused stats-finalize + BN + ReLU + bf16 + pointwise GEMM.
// out[b][o][p] = sum_c pw[o][c] * relu(bn(y[b][c][p])).
// B-operand reg-staged from rotated y16 (rotation is ks-invariant since
// ks*32*128 == 0 mod 4096), BN applied, ds_write-transposed into ldsB[p][c].
// Double-buffered ldsA/ldsB, ONE barrier per ks.
// ---------------------------------------------------------------------------
__global__ __launch_bounds__(256, 4) void gemm_kernel(
    const __hip_bfloat16* __restrict__ pwb, const _Float16* __restrict__ y16,
    const float* __restrict__ gsum, const float* __restrict__ gsumsq,
    const float* __restrict__ gamma, const float* __restrict__ beta,
    float* __restrict__ out)
{
    __shared__ __hip_bfloat16 ldsA[2][128 * 32];   // [o-row][c], 8KB each
    __shared__ unsigned short  ldsB[2][128 * 32];  // [p-row][c] bf16 bits
    __shared__ float scsh[512];                    // sc[256] | sh[256]

    const int tid  = threadIdx.x;
    const int lane = tid & 63;
    const int wid  = tid >> 6;
    const int b    = blockIdx.z;
    const int m0   = blockIdx.y * 128;
    const int p0   = blockIdx.x * 128;
    const int wm   = wid >> 1, wn = wid & 1;

    // Stats finalize, channel tid (redundant per block; trivial VALU).
    {
        const float inv = 1.f / 65536.f;
        const float mean = gsum[tid] * inv;
        const float var  = gsumsq[tid] * inv - mean * mean;
        const float sc   = gamma[tid] * rsqrtf(var + 1e-5f);
        scsh[tid]       = sc;
        scsh[256 + tid] = beta[tid] - mean * sc;
    }

    f32x4 acc[4][4];
#pragma unroll
    for (int mi = 0; mi < 4; ++mi)
#pragma unroll
        for (int ni = 0; ni < 4; ++ni) acc[mi][ni] = {0.f, 0.f, 0.f, 0.f};

    const int srow = lane >> 2;          // A staging
    const int scol = (lane & 3) * 8;
    const int fr   = lane & 15;          // fragment reads
    const int fk   = (lane >> 4) * 8;
    const int cb   = tid & 31;           // B staging: channel-within-ks
    const int pg   = tid >> 5;           // 8 groups x 16 p rows

    // Rotated pixel base (per-channel c*128 rotation, ks-invariant).
    const int rotpix = (p0 + pg * 16 + (cb << 7)) & 4095;
    const _Float16* __restrict__ yb =
        y16 + ((size_t)b * CB + cb) * HWp + rotpix;

    // Prologue: y for ks=0 into regs, A for ks=0 into ldsA[0].
    uint4 ya0 = *reinterpret_cast<const uint4*>(yb);
    uint4 ya1 = *reinterpret_cast<const uint4*>(yb + 8);
#pragma unroll
    for (int q = 0; q < 2; ++q) {
        const int issue = wid * 2 + q;
        const int row   = issue * 16 + srow;
        __builtin_amdgcn_global_load_lds(
            (gvoid*)(pwb + (size_t)(m0 + row) * CB + scol),
            (svoid*)(&ldsA[0][issue * 512]), 16, 0, 0);
    }
    __syncthreads();   // scsh + A0 + ya ready

    for (int ks = 0; ks < 8; ++ks) {
        const int cur = ks & 1;
        // BN + ReLU + bf16 on current y regs.
        const float scv = scsh[ks * 32 + cb];
        const float shv = scsh[256 + ks * 32 + cb];
        const f16x8 h0 = __builtin_bit_cast(f16x8, ya0);
        const f16x8 h1 = __builtin_bit_cast(f16x8, ya1);
        unsigned short rb[16];
#pragma unroll
        for (int e = 0; e < 8; ++e) {
            const __hip_bfloat16 v0 = __float2bfloat16(fmaxf(fmaf((float)h0[e], scv, shv), 0.f));
            const __hip_bfloat16 v1 = __float2bfloat16(fmaxf(fmaf((float)h1[e], scv, shv), 0.f));
            rb[e]     = __builtin_bit_cast(unsigned short, v0);
            rb[8 + e] = __builtin_bit_cast(unsigned short, v1);
        }
        // Transposed LDS write: ldsB[p][c], 16 x b16 (stride 64B).
        unsigned short* bw = &ldsB[cur][(pg * 16) * 32 + cb];
#pragma unroll
        for (int e = 0; e < 16; ++e) bw[e * 32] = rb[e];

        // Prefetch next ks before the barrier (drain doubles as wait).
        if (ks < 7) {
            const _Float16* yn = yb + (size_t)(ks + 1) * 32 * HWp;
            ya0 = *reinterpret_cast<const uint4*>(yn);
            ya1 = *reinterpret_cast<const uint4*>(yn + 8);
            const int k0 = (ks + 1) * 32;
#pragma unroll
            for (int q = 0; q < 2; ++q) {
                const int issue = wid * 2 + q;
                const int row   = issue * 16 + srow;
                __builtin_amdgcn_global_load_lds(
                    (gvoid*)(pwb + (size_t)(m0 + row) * CB + k0 + scol),
                    (svoid*)(&ldsA[cur ^ 1][issue * 512]), 16, 0, 0);
            }
        }
        __syncthreads();

        bf16x8 af[4], bfv[4];
#pragma unroll
        for (int mi = 0; mi < 4; ++mi)
            af[mi] = *reinterpret_cast<const bf16x8*>(
                &ldsA[cur][(wm * 64 + mi * 16 + fr) * 32 + fk]);
#pragma unroll
        for (int ni = 0; ni < 4; ++ni)
            bfv[ni] = *reinterpret_cast<const bf16x8*>(
                &ldsB[cur][(wn * 64 + ni * 16 + fr) * 32 + fk]);

#pragma unroll
        for (int mi = 0; mi < 4; ++mi)
#pragma unroll
            for (int ni = 0; ni < 4; ++ni)
                acc[mi][ni] = __builtin_amdgcn_mfma_f32_16x16x32_bf16(
                    af[mi], bfv[ni], acc[mi][ni], 0, 0, 0);
        // no second barrier: double-buffered, next writes go to cur^1
    }

    const int frow = (lane >> 4) * 4;
#pragma unroll
    for (int mi = 0; mi < 4; ++mi)
#pragma unroll
        for (int ni = 0; ni < 4; ++ni)
#pragma unroll
            for (int v = 0; v < 4; ++v) {
                const int o = m0 + wm * 64 + mi * 16 + frow + v;
                const int p = p0 + wn * 64 + ni * 16 + fr;
                out[((size_t)(b * CB + o)) * HWp + p] = acc[mi][ni][v];
            }
}

// ---------------------------------------------------------------------------
extern "C" void kernel_launch(void* const* d_in, const int* in_sizes, int n_in,
                              void* d_out, int out_size, void* d_ws, size_t ws_size,
                              hipStream_t stream) {
    (void)in_sizes; (void)n_in; (void)out_size; (void)ws_size;
    const float* x     = (const float*)d_in[0];
    const float* dw    = (const float*)d_in[1];
    const float* gamma = (const float*)d_in[2];
    const float* beta  = (const float*)d_in[3];
    const float* pw    = (const float*)d_in[4];
    float* out = (float*)d_out;

    // toep (32.5MB) lives in d_out and dies before gemm's stores.
    // ws: y16 (32MB) | gsum(256) gsumsq(256) | pad | pwb (128KB).
    char* ws = (char*)d_ws;
    uint4* toep   = (uint4*)d_out;
    _Float16* y16 = (_Float16*)ws;
    float* gsum   = (float*)(ws + (size_t)33554432);
    float* gsumsq = gsum + 256;
    __hip_bfloat16* pwb = (__hip_bfloat16*)(ws + (size_t)33554432 + 4096);

    prep_kernel<<<dim3(8000), 256, 0, stream>>>(pw, pwb, dw, toep, gsum);
    dwconv_kernel<<<dim3(2048), 256, 0, stream>>>(x, toep, y16, gsum, gsumsq);
    gemm_kernel<<<dim3(32, 2, NB), 256, 0, stream>>>(pwb, y16, gsum, gsumsq,
                                                     gamma, beta, out);
}